// Round 1
// baseline (474.126 us; speedup 1.0000x reference)
//
#include <hip/hip_runtime.h>

#define IN_F 256
#define OUT_F 64

// ---------------------------------------------------------------- zero / relu
__global__ __launch_bounds__(256) void zero_kernel(float* __restrict__ p, int n4) {
    int i = blockIdx.x * 256 + threadIdx.x;
    if (i < n4) {
        float4 z = {0.f, 0.f, 0.f, 0.f};
        ((float4*)p)[i] = z;
    }
}

__global__ __launch_bounds__(256) void relu_kernel(float* __restrict__ p, int n4) {
    int i = blockIdx.x * 256 + threadIdx.x;
    if (i < n4) {
        float4 v = ((float4*)p)[i];
        v.x = fmaxf(v.x, 0.f);
        v.y = fmaxf(v.y, 0.f);
        v.z = fmaxf(v.z, 0.f);
        v.w = fmaxf(v.w, 0.f);
        ((float4*)p)[i] = v;
    }
}

// ---------------------------------------------------------------- GEMM h = feat @ W
// feat [N][256] fp32, W [256][64] fp32, h [N][64] fp32.
// Block = 256 threads covering 64 rows x 64 cols; each thread computes a
// 4-row x 4-col micro-tile. W rows are read as float4, coalesced across the
// 16-lane column groups; feat reads broadcast across those lanes (L1-served).
__global__ __launch_bounds__(256) void gemm_kernel(const float* __restrict__ feat,
                                                   const float* __restrict__ W,
                                                   float* __restrict__ h, int N) {
    const int tid = threadIdx.x;
    const int cg = tid & 15;   // column group: cols 4*cg .. 4*cg+3
    const int rg = tid >> 4;   // row group: rows row0 .. row0+3
    const int row0 = blockIdx.x * 64 + rg * 4;

    const float4* __restrict__ feat4 = (const float4*)feat; // [N][64]
    const float4* __restrict__ W4 = (const float4*)W;       // [256][16]

    // clamp rows for loads (duplicates are harmless; stores are guarded)
    const int r0 = min(row0 + 0, N - 1);
    const int r1 = min(row0 + 1, N - 1);
    const int r2 = min(row0 + 2, N - 1);
    const int r3 = min(row0 + 3, N - 1);

    float4 acc0 = {0.f, 0.f, 0.f, 0.f};
    float4 acc1 = {0.f, 0.f, 0.f, 0.f};
    float4 acc2 = {0.f, 0.f, 0.f, 0.f};
    float4 acc3 = {0.f, 0.f, 0.f, 0.f};

#define FMA4(ACC, A, B)                                                        \
    ACC.x = fmaf(A, B.x, ACC.x);                                               \
    ACC.y = fmaf(A, B.y, ACC.y);                                               \
    ACC.z = fmaf(A, B.z, ACC.z);                                               \
    ACC.w = fmaf(A, B.w, ACC.w);

#pragma unroll 4
    for (int k = 0; k < IN_F; k += 4) {
        const int k4 = k >> 2;
        float4 a0 = feat4[r0 * (IN_F / 4) + k4];
        float4 a1 = feat4[r1 * (IN_F / 4) + k4];
        float4 a2 = feat4[r2 * (IN_F / 4) + k4];
        float4 a3 = feat4[r3 * (IN_F / 4) + k4];
        float4 b0 = W4[(k + 0) * (OUT_F / 4) + cg];
        float4 b1 = W4[(k + 1) * (OUT_F / 4) + cg];
        float4 b2 = W4[(k + 2) * (OUT_F / 4) + cg];
        float4 b3 = W4[(k + 3) * (OUT_F / 4) + cg];

        FMA4(acc0, a0.x, b0); FMA4(acc0, a0.y, b1); FMA4(acc0, a0.z, b2); FMA4(acc0, a0.w, b3);
        FMA4(acc1, a1.x, b0); FMA4(acc1, a1.y, b1); FMA4(acc1, a1.z, b2); FMA4(acc1, a1.w, b3);
        FMA4(acc2, a2.x, b0); FMA4(acc2, a2.y, b1); FMA4(acc2, a2.z, b2); FMA4(acc2, a2.w, b3);
        FMA4(acc3, a3.x, b0); FMA4(acc3, a3.y, b1); FMA4(acc3, a3.z, b2); FMA4(acc3, a3.w, b3);
    }
#undef FMA4

    float4* __restrict__ h4 = (float4*)h; // [N][16]
    if (row0 + 0 < N) h4[(row0 + 0) * (OUT_F / 4) + cg] = acc0;
    if (row0 + 1 < N) h4[(row0 + 1) * (OUT_F / 4) + cg] = acc1;
    if (row0 + 2 < N) h4[(row0 + 2) * (OUT_F / 4) + cg] = acc2;
    if (row0 + 3 < N) h4[(row0 + 3) * (OUT_F / 4) + cg] = acc3;
}

// ---------------------------------------------------------------- edge scatter
// One 64-lane wave per edge; lane = output column.
__global__ __launch_bounds__(256) void scatter_kernel(const float* __restrict__ h,
                                                      const float* __restrict__ ew,
                                                      const int* __restrict__ src,
                                                      const int* __restrict__ dst,
                                                      float* __restrict__ out, int E) {
    int gid = blockIdx.x * 256 + threadIdx.x;
    int e = gid >> 6;
    int lane = gid & 63;
    if (e < E) {
        int s = src[e];
        int d = dst[e];
        float w = ew[e];
        float v = h[s * OUT_F + lane] * w;
        atomicAdd(&out[d * OUT_F + lane], v);
    }
}

// ---------------------------------------------------------------- launch
extern "C" void kernel_launch(void* const* d_in, const int* in_sizes, int n_in,
                              void* d_out, int out_size, void* d_ws, size_t ws_size,
                              hipStream_t stream) {
    const float* feat = (const float*)d_in[0];
    const float* W    = (const float*)d_in[1];
    const float* ew   = (const float*)d_in[2];
    const int*   src  = (const int*)d_in[3];
    const int*   dst  = (const int*)d_in[4];
    float* out = (float*)d_out;
    float* h   = (float*)d_ws; // [N][64] fp32 scratch = 25.6 MB

    const int N = in_sizes[0] / IN_F;
    const int E = in_sizes[2];
    const int n4 = (N * OUT_F) / 4;

    hipLaunchKernelGGL(zero_kernel, dim3((n4 + 255) / 256), dim3(256), 0, stream, out, n4);
    hipLaunchKernelGGL(gemm_kernel, dim3((N + 63) / 64), dim3(256), 0, stream, feat, W, h, N);
    const int sblocks = (E * 64 + 255) / 256;
    hipLaunchKernelGGL(scatter_kernel, dim3(sblocks), dim3(256), 0, stream, h, ew, src, dst, out, E);
    hipLaunchKernelGGL(relu_kernel, dim3((n4 + 255) / 256), dim3(256), 0, stream, out, n4);
}